// Round 15
// baseline (320.224 us; speedup 1.0000x reference)
//
#include <hip/hip_runtime.h>

// ---------------------------------------------------------------------------
// GCN: x1 = relu(Ahat @ (fts@W1) + b1); x2 = relu(Ahat @ (x1@W2) + b2);
//      out = x2@Wc + bc.  Ahat = D^-1/2 (A + I) D^-1/2.
// d_out = [out (N*16) | x2 (N*128)] fp32.
// R2-R13: scan/gather/MFMA/slot-capture/8-replica/fma_mix ladder.
// R10,R14/15,R18/19,R20,R22 ALL FAILED the same way: static partitions,
//      manual prefetch, and concurrent-kernel fusion each stole TLP from
//      latency-bound phases. RULE: every phase here wants the whole
//      machine; give the HW scheduler many small independent blocks.
// R16/R17: NPW=4 (agg2) / NPW=1 (agg1). 257.0us.
// R21: merged scan via atomic block-ticket. 253.3us.
// R23: packed int2 row extents. agg2 43.6->41.3; total 253.3 BEST.
// R24: (a) u16-packed slots: thread's 8 slots = one uint4 (16B not 32B);
//      slot traffic halves in count AND fill (values <= deg << 65k).
//      (b) CLS LDS de-conflict: both WcT/h2s reads had all 4 grps on
//      128B-aligned k-slices (grp*32 % 32 == 0 -> same bank). Intra-row
//      pad k -> k+(k>>5) puts slice g at g*33 (banks decoupled); WcT rows
//      padded to 133 (odd stride spreads pos). float4 reads still
//      contiguous (pads only at 32-boundaries). 2.0M conflicts -> ~0.4M.
// ---------------------------------------------------------------------------

#define IN_DIM 256
#define HID 128
#define OUT_DIM 16
#define SCAN_B 256
#define NREP 8

typedef _Float16 half8  __attribute__((ext_vector_type(8)));
typedef float    floatx4 __attribute__((ext_vector_type(4)));

// acc[0..7] += fp16 elements of u (4 dwords, lo/hi halves), exact, 1 VALU each.
__device__ __forceinline__ void accum8(float* acc, uint4 u, float onef) {
    asm("v_fma_mix_f32 %0, %1, %2, %0 op_sel:[0,0,0] op_sel_hi:[1,0,0]"
        : "+v"(acc[0]) : "v"(u.x), "v"(onef));
    asm("v_fma_mix_f32 %0, %1, %2, %0 op_sel:[1,0,0] op_sel_hi:[1,0,0]"
        : "+v"(acc[1]) : "v"(u.x), "v"(onef));
    asm("v_fma_mix_f32 %0, %1, %2, %0 op_sel:[0,0,0] op_sel_hi:[1,0,0]"
        : "+v"(acc[2]) : "v"(u.y), "v"(onef));
    asm("v_fma_mix_f32 %0, %1, %2, %0 op_sel:[1,0,0] op_sel_hi:[1,0,0]"
        : "+v"(acc[3]) : "v"(u.y), "v"(onef));
    asm("v_fma_mix_f32 %0, %1, %2, %0 op_sel:[0,0,0] op_sel_hi:[1,0,0]"
        : "+v"(acc[4]) : "v"(u.z), "v"(onef));
    asm("v_fma_mix_f32 %0, %1, %2, %0 op_sel:[1,0,0] op_sel_hi:[1,0,0]"
        : "+v"(acc[5]) : "v"(u.z), "v"(onef));
    asm("v_fma_mix_f32 %0, %1, %2, %0 op_sel:[0,0,0] op_sel_hi:[1,0,0]"
        : "+v"(acc[6]) : "v"(u.w), "v"(onef));
    asm("v_fma_mix_f32 %0, %1, %2, %0 op_sel:[1,0,0] op_sel_hi:[1,0,0]"
        : "+v"(acc[7]) : "v"(u.w), "v"(onef));
}

__device__ __forceinline__ void wswz_one(const float* W, _Float16* Bsw, int o, int permK) {
    int j    = o & 7;
    int lane = (o >> 3) & 63;
    int t    = (o >> 9) & 7;
    int c    = o >> 12;
    int k = c * 32 + ((lane >> 4) << 3) + j;
    if (permK) k = ((k & 7) << 4) + (k >> 3);
    int ncol = t * 16 + (lane & 15);
    Bsw[o] = (_Float16)W[k * 128 + ncol];
}

// Fused prep: zero rep planes + ticket; swizzle W1,W2; permute biases.
__global__ void k_prep(int* __restrict__ rep, int nrepN, int* __restrict__ gtick,
                       const float* __restrict__ W1, _Float16* __restrict__ Bsw1,
                       const float* __restrict__ W2, _Float16* __restrict__ Bsw2,
                       const float* __restrict__ b1, float* __restrict__ bp1,
                       const float* __restrict__ b2, float* __restrict__ bp2) {
    int t = blockIdx.x * blockDim.x + threadIdx.x;
    if (t == 0) gtick[0] = 0;
    int z4 = nrepN >> 2;
    int zr = z4 + (nrepN & 3);
    if (t < z4) { ((int4*)rep)[t] = make_int4(0, 0, 0, 0); return; }
    if (t < zr) { rep[4 * z4 + (t - z4)] = 0; return; }
    int o = t - zr;
    if (o < IN_DIM * HID) { wswz_one(W1, Bsw1, o, 0); return; }
    o -= IN_DIM * HID;
    if (o < HID * HID) { wswz_one(W2, Bsw2, o, 1); return; }
    o -= HID * HID;
    if (o < HID) { bp1[o] = b1[((o & 7) << 4) + (o >> 3)]; return; }
    o -= HID;
    if (o < HID) { bp2[o] = b2[((o & 7) << 4) + (o >> 3)]; return; }
}

// Thread i owns edges 8i..8i+7; edge 8i+k bumps replica plane k.
// Slots packed as 8 x u16 = one uint4 per thread (R24).
__global__ void k_count(const int* __restrict__ dst, int* __restrict__ rep,
                        unsigned short* __restrict__ slot, int nN, int e8, int e) {
    int i = blockIdx.x * blockDim.x + threadIdx.x;
    if (i < e8) {
        int4 d0 = ((const int4*)dst)[2 * i];
        int4 d1 = ((const int4*)dst)[2 * i + 1];
        int4 s0, s1;
        s0.x = atomicAdd(&rep[0 * nN + d0.x], 1);
        s0.y = atomicAdd(&rep[1 * nN + d0.y], 1);
        s0.z = atomicAdd(&rep[2 * nN + d0.z], 1);
        s0.w = atomicAdd(&rep[3 * nN + d0.w], 1);
        s1.x = atomicAdd(&rep[4 * nN + d1.x], 1);
        s1.y = atomicAdd(&rep[5 * nN + d1.y], 1);
        s1.z = atomicAdd(&rep[6 * nN + d1.z], 1);
        s1.w = atomicAdd(&rep[7 * nN + d1.w], 1);
        uint4 sp;
        sp.x = ((unsigned)s0.y << 16) | ((unsigned)s0.x & 0xffffu);
        sp.y = ((unsigned)s0.w << 16) | ((unsigned)s0.z & 0xffffu);
        sp.z = ((unsigned)s1.y << 16) | ((unsigned)s1.x & 0xffffu);
        sp.w = ((unsigned)s1.w << 16) | ((unsigned)s1.z & 0xffffu);
        ((uint4*)slot)[i] = sp;
    }
    int base = e8 * 8;
    int t = blockIdx.x * blockDim.x + threadIdx.x;
    if (t < e - base) {
        int j = base + t;
        slot[j] = (unsigned short)atomicAdd(&rep[(j & 7) * nN + dst[j]], 1);
    }
}

// Merged scan (R21): plane offsets in regs -> LDS scan of node totals ->
// block base via atomic ticket -> write rbe/dinv + baked planes.
__global__ __launch_bounds__(SCAN_B) void k_scan(int* __restrict__ rep,
                                                 int2* __restrict__ rbe,
                                                 float* __restrict__ dinv,
                                                 int* __restrict__ gtick,
                                                 int nN, int n) {
    __shared__ int tmp[SCAN_B];
    __shared__ int sbase;
    int tid = threadIdx.x;
    int i = blockIdx.x * SCAN_B + tid;
    int off[NREP];
    int c = 0;
    if (i < n) {
        #pragma unroll
        for (int r = 0; r < NREP; ++r) {
            int t = rep[r * nN + i];
            off[r] = c;
            c += t;
        }
    }
    tmp[tid] = c;
    __syncthreads();
    #pragma unroll
    for (int o = 1; o < SCAN_B; o <<= 1) {
        int v = (tid >= o) ? tmp[tid - o] : 0;
        __syncthreads();
        tmp[tid] += v;
        __syncthreads();
    }
    if (tid == SCAN_B - 1) sbase = atomicAdd(gtick, tmp[tid]);
    __syncthreads();
    int base = sbase;
    if (i < n) {
        int rp = base + tmp[tid] - c;
        rbe[i] = make_int2(rp, rp + c);     // packed extent: ONE 8B load in agg
        dinv[i] = rsqrtf((float)(c + 1));   // +1 self-loop
        #pragma unroll
        for (int r = 0; r < NREP; ++r) rep[r * nN + i] = off[r] + rp;
    }
}

// Atomic-free scatter: col[rep[k][dst] + slot] = src. Slots read packed u16.
__global__ void k_fill(const int* __restrict__ src, const int* __restrict__ dst,
                       const unsigned short* __restrict__ slot,
                       const int* __restrict__ rep,
                       int* __restrict__ col, int nN, int e8, int e) {
    int i = blockIdx.x * blockDim.x + threadIdx.x;
    if (i < e8) {
        int4 v0 = ((const int4*)src)[2 * i];
        int4 v1 = ((const int4*)src)[2 * i + 1];
        int4 d0 = ((const int4*)dst)[2 * i];
        int4 d1 = ((const int4*)dst)[2 * i + 1];
        uint4 sp = ((const uint4*)slot)[i];
        col[rep[0 * nN + d0.x] + (int)(sp.x & 0xffffu)] = v0.x;
        col[rep[1 * nN + d0.y] + (int)(sp.x >> 16)]     = v0.y;
        col[rep[2 * nN + d0.z] + (int)(sp.y & 0xffffu)] = v0.z;
        col[rep[3 * nN + d0.w] + (int)(sp.y >> 16)]     = v0.w;
        col[rep[4 * nN + d1.x] + (int)(sp.z & 0xffffu)] = v1.x;
        col[rep[5 * nN + d1.y] + (int)(sp.z >> 16)]     = v1.y;
        col[rep[6 * nN + d1.z] + (int)(sp.w & 0xffffu)] = v1.z;
        col[rep[7 * nN + d1.w] + (int)(sp.w >> 16)]     = v1.w;
    }
    int base = e8 * 8;
    int t = blockIdx.x * blockDim.x + threadIdx.x;
    if (t < e - base) {
        int j = base + t;
        col[rep[(j & 7) * nN + dst[j]] + (int)slot[j]] = src[j];
    }
}

// Cb[n,128](fp16, pi-permuted cols) = dinv[row] * (A[n,K] @ W[K,128]).
template<bool A32>
__global__ __launch_bounds__(256) void k_gemm_mfma(const void* __restrict__ Av,
                                                   const _Float16* __restrict__ Bsw,
                                                   _Float16* __restrict__ Cb,
                                                   const float* __restrict__ dinv,
                                                   int n, int K) {
    int tid   = threadIdx.x;
    int w     = tid >> 6;
    int ln    = tid & 63;
    int lane16 = ln & 15;
    int quad  = ln >> 4;
    int mrow  = blockIdx.x * 64 + w * 16 + lane16;
    int mload = mrow < n ? mrow : n - 1;
    int nchunk = K >> 5;

    floatx4 acc[8];
    #pragma unroll
    for (int t = 0; t < 8; ++t) acc[t] = (floatx4){0.f, 0.f, 0.f, 0.f};

    for (int c = 0; c < nchunk; ++c) {
        half8 a;
        if constexpr (A32) {
            const float* ap = (const float*)Av + (size_t)mload * K + c * 32 + quad * 8;
            float4 v0 = *(const float4*)ap;
            float4 v1 = *(const float4*)(ap + 4);
            a[0] = (_Float16)v0.x; a[1] = (_Float16)v0.y;
            a[2] = (_Float16)v0.z; a[3] = (_Float16)v0.w;
            a[4] = (_Float16)v1.x; a[5] = (_Float16)v1.y;
            a[6] = (_Float16)v1.z; a[7] = (_Float16)v1.w;
        } else {
            const _Float16* ap = (const _Float16*)Av + (size_t)mload * K + c * 32 + quad * 8;
            a = *(const half8*)ap;
        }
        const _Float16* bp = Bsw + ((size_t)(c * 8) * 64 + ln) * 8;
        #pragma unroll
        for (int t = 0; t < 8; ++t) {
            half8 b = *(const half8*)(bp + (size_t)t * 512);
            acc[t] = __builtin_amdgcn_mfma_f32_16x16x32_f16(a, b, acc[t], 0, 0, 0);
        }
    }

    int rbase = blockIdx.x * 64 + w * 16 + quad * 4;
    #pragma unroll
    for (int r = 0; r < 4; ++r) {
        int R = rbase + r;
        if (R < n) {
            float d = dinv[R];
            half8 o;
            #pragma unroll
            for (int t = 0; t < 8; ++t) o[t] = (_Float16)(acc[t][r] * d);
            *(half8*)(Cb + (size_t)R * 128 + lane16 * 8) = o;
        }
    }
}

// One wave per node. NPW=1 (agg1, max TLP) / NPW=4 (agg2, WcT amortized).
// Extent = rbe[i] (packed int2). CLS LDS uses intra-row padding (R24):
// element k lives at k+(k>>5), so grp's k-slice starts at grp*33 -> banks
// decoupled; WcT row stride 133 spreads pos. float4 reads stay contiguous.
template<bool OUT16, bool CLS, int NPW>
__global__ __launch_bounds__(256) void k_agg(const _Float16* __restrict__ xwb,
                                             const float* __restrict__ dinv,
                                             const int2* __restrict__ rbe,
                                             const int* __restrict__ col,
                                             const float* __restrict__ bp,
                                             void* __restrict__ hout,
                                             const float* __restrict__ Wc,
                                             const float* __restrict__ bc,
                                             float* __restrict__ outp,
                                             int n) {
    __shared__ float WcT[CLS ? 16 * 133 : 1];   // [c][k+(k>>5)], row stride 133
    __shared__ float h2s[CLS ? 4 * 132 : 1];    // per-wave h2 row, k+(k>>5)

    int wave = threadIdx.x >> 6;
    int ln   = threadIdx.x & 63;
    int grp  = ln >> 4;          // 0..3: which edge of each quad
    int pos  = ln & 15;          // 16B segment within the 256B row

    if constexpr (CLS) {
        // Wc[128][16] row-major -> WcT[c*133 + k + (k>>5)]; coalesced reads.
        for (int t = threadIdx.x; t < 128 * OUT_DIM; t += 256) {
            int k = t >> 4, c = t & 15;
            WcT[c * 133 + k + (k >> 5)] = Wc[t];
        }
        __syncthreads();         // before any early return (barrier safety)
    }

    const _Float16* xb = xwb + pos * 8;
    float onef = 1.0f;

    // ---- node-independent operands: once per wave ----
    float4 bq0 = *(const float4*)(bp + pos * 8);
    float4 bq1 = *(const float4*)(bp + pos * 8 + 4);
    float bb[8] = {bq0.x, bq0.y, bq0.z, bq0.w, bq1.x, bq1.y, bq1.z, bq1.w};
    float bcv = 0.f;
    if constexpr (CLS) bcv = bc[pos];

    int i0 = (blockIdx.x * 4 + wave) * NPW;
    if (i0 >= n) return;

    #pragma unroll 1
    for (int it = 0; it < NPW; ++it) {
        int i = i0 + it;
        if (NPW > 1 && i >= n) break;
        int2 ee = rbe[i];                // packed: one 8B load
        int e0 = ee.x, e1 = ee.y;

        // self-row + dinv issued before the gather chain
        uint4 usu = *(const uint4*)(xb + (size_t)i * 128);
        float di  = dinv[i];

        float acc[8];
        #pragma unroll
        for (int j = 0; j < 8; ++j) acc[j] = 0.f;

        int e = e0 + grp;
        if (e + 12 < e1) {
            int s0 = col[e], s1 = col[e + 4], s2 = col[e + 8], s3 = col[e + 12];
            while (true) {
                int en = e + 16;
                bool more = (en + 12 < e1);
                int t0, t1, t2, t3;
                if (more) {            // prefetch next quad's indices
                    t0 = col[en]; t1 = col[en + 4]; t2 = col[en + 8]; t3 = col[en + 12];
                }
                uint4 u0 = *(const uint4*)(xb + (size_t)s0 * 128);
                uint4 u1 = *(const uint4*)(xb + (size_t)s1 * 128);
                uint4 u2 = *(const uint4*)(xb + (size_t)s2 * 128);
                uint4 u3 = *(const uint4*)(xb + (size_t)s3 * 128);
                accum8(acc, u0, onef);
                accum8(acc, u1, onef);
                accum8(acc, u2, onef);
                accum8(acc, u3, onef);
                e = en;
                if (!more) break;
                s0 = t0; s1 = t1; s2 = t2; s3 = t3;
            }
        }
        // remainder: unroll-2, both gathers in flight (tail ILP)
        for (; e + 4 < e1; e += 8) {
            int sa = col[e], sb = col[e + 4];
            uint4 ua = *(const uint4*)(xb + (size_t)sa * 128);
            uint4 ub = *(const uint4*)(xb + (size_t)sb * 128);
            accum8(acc, ua, onef);
            accum8(acc, ub, onef);
        }
        if (e < e1) {
            int s = col[e];
            uint4 u = *(const uint4*)(xb + (size_t)s * 128);
            accum8(acc, u, onef);
        }

        // combine the 4 groups (lanes xor 16, xor 32)
        #pragma unroll
        for (int j = 0; j < 8; ++j) {
            acc[j] += __shfl_xor(acc[j], 16, 64);
            acc[j] += __shfl_xor(acc[j], 32, 64);
        }

        // self-loop (exact fp16->fp32 fma_mix adds)
        accum8(acc, usu, onef);

        float ov[8];
        #pragma unroll
        for (int j = 0; j < 8; ++j)
            ov[j] = fmaxf(fmaf(di, acc[j], bb[j]), 0.f);

        if constexpr (OUT16) {
            if (grp == 0) {
                half8 o;
                #pragma unroll
                for (int j = 0; j < 8; ++j) o[j] = (_Float16)ov[j];
                *(half8*)((_Float16*)hout + (size_t)i * 128 + pos * 8) = o;
            }
        } else {
            // position p = pos*8+j holds col j*16+pos; all-lane split: grp g
            // stores j=2g,2g+1 -> 2 stores/lane, wave covers the 512B row.
            float* hf = (float*)hout + (size_t)i * 128;
            #pragma unroll
            for (int h = 0; h < 2; ++h) {
                int j = 2 * grp + h;
                hf[j * 16 + pos] = ov[j];
                if constexpr (CLS) {
                    int k = j * 16 + pos;
                    h2s[wave * 132 + k + (k >> 5)] = ov[j];
                }
            }
        }

        if constexpr (CLS) {
            // out[i][c=pos] = sum_k h2[k] * WcT[pos][k] + bc[pos];
            // lane covers k = grp*32 .. grp*32+31 (at padded base grp*33),
            // then reduce over grp. Wave-private LDS: no barrier needed.
            const float* wrow = &WcT[pos * 133 + grp * 33];
            const float* hrow = &h2s[wave * 132 + grp * 33];   // broadcast reads
            float pt = 0.f;
            #pragma unroll
            for (int kk = 0; kk < 32; kk += 4) {
                float4 wv = *(const float4*)(wrow + kk);
                float4 hv = *(const float4*)(hrow + kk);
                pt = fmaf(hv.x, wv.x, pt);
                pt = fmaf(hv.y, wv.y, pt);
                pt = fmaf(hv.z, wv.z, pt);
                pt = fmaf(hv.w, wv.w, pt);
            }
            pt += __shfl_xor(pt, 16, 64);
            pt += __shfl_xor(pt, 32, 64);
            if (grp == 0) outp[(size_t)i * OUT_DIM + pos] = pt + bcv;
        }
    }
}

static inline size_t align256(size_t x) { return (x + 255) & ~(size_t)255; }

extern "C" void kernel_launch(void* const* d_in, const int* in_sizes, int n_in,
                              void* d_out, int out_size, void* d_ws, size_t ws_size,
                              hipStream_t stream) {
    const float* fts = (const float*)d_in[0];
    const int*   ei  = (const int*)d_in[1];
    const float* W1  = (const float*)d_in[2];
    const float* b1  = (const float*)d_in[3];
    const float* W2  = (const float*)d_in[4];
    const float* b2  = (const float*)d_in[5];
    const float* Wc  = (const float*)d_in[6];
    const float* bc  = (const float*)d_in[7];

    const int N = in_sizes[0] / IN_DIM;     // 50000
    const int E = in_sizes[1] / 2;          // 800000
    const int* src = ei;
    const int* dst = ei + E;

    char* p = (char*)d_ws;
    int* rep      = (int*)p;               p += align256(sizeof(int) * NREP * N);
    int2* rbe     = (int2*)p;              p += align256(sizeof(int2) * N);
    float* dinv   = (float*)p;             p += align256(sizeof(float) * N);
    unsigned short* slot = (unsigned short*)p;  p += align256(sizeof(unsigned short) * E);
    int* col      = (int*)p;               p += align256(sizeof(int) * (E + 16));
    int* gtick    = (int*)p;               p += align256(sizeof(int) * 16);
    _Float16* Bsw1 = (_Float16*)p;         p += align256(sizeof(_Float16) * IN_DIM * HID);
    _Float16* Bsw2 = (_Float16*)p;         p += align256(sizeof(_Float16) * HID * HID);
    float* bp1    = (float*)p;             p += align256(sizeof(float) * HID);
    float* bp2    = (float*)p;             p += align256(sizeof(float) * HID);
    _Float16* xwb = (_Float16*)p;          p += align256(sizeof(_Float16) * (size_t)N * HID);
    _Float16* h1  = (_Float16*)p;          p += align256(sizeof(_Float16) * (size_t)N * HID);

    float* out = (float*)d_out;                   // [N,16]
    float* h2  = (float*)d_out + (size_t)N * 16;  // [N,128]

    const int T = 256;
    const int E8 = E / 8;
    dim3 gE8((E8 + T - 1) / T);
    const int nScanB = (N + SCAN_B - 1) / SCAN_B;

    // Fused prep (rep+ticket zero + W swizzles + bias perms)
    const int nrepN = NREP * N;
    const int zr = (nrepN >> 2) + (nrepN & 3);
    const int prepTot = zr + IN_DIM * HID + HID * HID + 2 * HID;
    k_prep<<<(prepTot + T - 1) / T, T, 0, stream>>>(rep, nrepN, gtick, W1, Bsw1, W2, Bsw2,
                                                    b1, bp1, b2, bp2);
    // Graph structure (count -> merged scan -> fill)
    k_count<<<gE8, T, 0, stream>>>(dst, rep, slot, N, E8, E);
    k_scan<<<nScanB, SCAN_B, 0, stream>>>(rep, rbe, dinv, gtick, N, N);
    k_fill<<<gE8, T, 0, stream>>>(src, dst, slot, rep, col, N, E8, E);

    dim3 gGemm((N + 63) / 64);
    dim3 gAgg1((N + 3) / 4);            // NPW=1: 12500 blocks (max TLP)
    dim3 gAgg2((N + 15) / 16);          // NPW=4: 3125 blocks (amortized CLS)

    // Layer 1
    k_gemm_mfma<true><<<gGemm, T, 0, stream>>>(fts, Bsw1, xwb, dinv, N, IN_DIM);
    k_agg<true, false, 1><<<gAgg1, T, 0, stream>>>(xwb, dinv, rbe, col, bp1, h1,
                                                   nullptr, nullptr, nullptr, N);
    // Layer 2
    k_gemm_mfma<false><<<gGemm, T, 0, stream>>>(h1, Bsw2, xwb, dinv, N, HID);
    // Aggregation + fused classifier
    k_agg<false, true, 4><<<gAgg2, T, 0, stream>>>(xwb, dinv, rbe, col, bp2, h2,
                                                   Wc, bc, out, N);
}